// Round 7
// baseline (117.702 us; speedup 1.0000x reference)
//
#include <hip/hip_runtime.h>
#include <stdint.h>

#define NUM_NODES 50000
#define B_ 4096
#define N_ 100

typedef float f32x4 __attribute__((ext_vector_type(4)));
typedef float f32x2 __attribute__((ext_vector_type(2)));
typedef short s16x8 __attribute__((ext_vector_type(8)));

__device__ inline unsigned short f2bf(float f) {
    unsigned u = __float_as_uint(f);
    u += 0x7fffu + ((u >> 16) & 1u);
    return (unsigned short)(u >> 16);
}

// wave64 sum-reduce on the VALU pipe (DPP), result broadcast to all lanes.
template <int CTRL>
__device__ inline float dpp_add(float x) {
    int t = __builtin_amdgcn_update_dpp(0, __float_as_int(x), CTRL, 0xf, 0xf, true);
    return x + __int_as_float(t);
}
__device__ inline float wave_sum64(float x) {
    x = dpp_add<0x111>(x);   // row_shr:1
    x = dpp_add<0x112>(x);   // row_shr:2
    x = dpp_add<0x114>(x);   // row_shr:4
    x = dpp_add<0x118>(x);   // row_shr:8
    x = dpp_add<0x142>(x);   // row_bcast:15
    x = dpp_add<0x143>(x);   // row_bcast:31
    return __int_as_float(__builtin_amdgcn_readlane(__float_as_int(x), 63));
}

// ---------------------------------------------------------------------------
// k_pre: blocks 0..1562 -> node_proj = node_raw @ W_feat + b_feat, skill
//        last block     -> WgT, hb, wm[11], Mtil[11][11]
// ---------------------------------------------------------------------------
__global__ __launch_bounds__(256) void k_pre(
    const float* __restrict__ node_raw, const float* __restrict__ W_feat,
    const float* __restrict__ b_feat, const float* __restrict__ W_gcn,
    const float* __restrict__ ln_g, const float* __restrict__ ln_b,
    const float* __restrict__ W_edge, const float* __restrict__ b_edge,
    const float* __restrict__ W_time, const float* __restrict__ b_time,
    const float* __restrict__ W_struct, const float* __restrict__ b_struct,
    float* __restrict__ proj, int* __restrict__ skill,
    unsigned short* __restrict__ WgT, float* __restrict__ hb,
    float* __restrict__ wmg, float* __restrict__ Mg)
{
    __shared__ float red[4][64];
    __shared__ float Ws[128 * 64];          // 32 KiB staged W_feat
    int blk = blockIdx.x;
    int t = threadIdx.x;
    int dj = t & 63;

    if (blk == gridDim.x - 1) {             // params block
        int g = t >> 6;                     // dk quarter
        float acc = 0.f;
        #pragma unroll
        for (int i = 0; i < 16; ++i) {
            int dk = g * 16 + i;
            float wv = W_gcn[dk * 64 + dj];
            WgT[dj * 64 + dk] = f2bf(ln_g[dk] * wv);
            acc += ln_b[dk] * wv;
        }
        red[g][dj] = acc;

        // wave 0: column means + centered Gram for LN-stat precompute
        if (t < 64) {
            int d = t;
            float col[11];
            col[0] = W_edge[d];
            col[1] = W_struct[d];
            #pragma unroll
            for (int i = 0; i < 8; ++i) col[2 + i] = W_time[i * 64 + d];
            col[10] = b_edge[d] + b_time[d] + 2.f * b_struct[d];
            float wmv[11];
            #pragma unroll
            for (int j = 0; j < 11; ++j) wmv[j] = wave_sum64(col[j]) * (1.f / 64.f);
            float cc[11];
            #pragma unroll
            for (int j = 0; j < 11; ++j) cc[j] = col[j] - wmv[j];
            #pragma unroll
            for (int j = 0; j < 11; ++j) {
                #pragma unroll
                for (int k = j; k < 11; ++k) {
                    float m = wave_sum64(cc[j] * cc[k]);
                    if (t == 0) { Mg[j * 11 + k] = m; Mg[k * 11 + j] = m; }
                }
            }
            if (t == 0) {
                #pragma unroll
                for (int j = 0; j < 11; ++j) wmg[j] = wmv[j];
            }
        }
        __syncthreads();
        if (g == 0) hb[dj] = red[0][dj] + red[1][dj] + red[2][dj] + red[3][dj];
        return;
    }

    // stage W_feat (128x64 f32 = 8192 elems): 32 coalesced rounds
    #pragma unroll
    for (int i = 0; i < 32; ++i) Ws[t + i * 256] = W_feat[t + i * 256];
    __syncthreads();

    int rg = t >> 6;
    int r0 = blk * 32 + rg * 8;
    float acc[8];
    #pragma unroll
    for (int r = 0; r < 8; ++r) acc[r] = 0.f;

    for (int k = 0; k < 128; k += 4) {
        float w0 = Ws[(k + 0) * 64 + dj];
        float w1 = Ws[(k + 1) * 64 + dj];
        float w2 = Ws[(k + 2) * 64 + dj];
        float w3 = Ws[(k + 3) * 64 + dj];
        #pragma unroll
        for (int r = 0; r < 8; ++r) {
            int row = r0 + r;
            int rc = row < NUM_NODES ? row : (NUM_NODES - 1);
            f32x4 rv = *(const f32x4*)(node_raw + (size_t)rc * 128 + k);
            acc[r] += rv.x * w0 + rv.y * w1 + rv.z * w2 + rv.w * w3;
        }
    }
    float bfv = b_feat[dj];
    #pragma unroll
    for (int r = 0; r < 8; ++r) {
        int row = r0 + r;
        if (row < NUM_NODES) proj[(size_t)row * 64 + dj] = acc[r] + bfv;
    }
    if (t < 32) {
        int row = blk * 32 + t;
        if (row < NUM_NODES) skill[row] = (int)node_raw[(size_t)row * 128];
    }
}

// ---------------------------------------------------------------------------
// k_stat: per-node LN stats. Block = 256 nodes tiled through LDS.
//   stats[node][16] = { pm, pc2, pcw[0..10], pad }
// ---------------------------------------------------------------------------
__global__ __launch_bounds__(256) void k_stat(
    const float* __restrict__ proj,
    const float* __restrict__ W_edge, const float* __restrict__ b_edge,
    const float* __restrict__ W_time, const float* __restrict__ b_time,
    const float* __restrict__ W_struct, const float* __restrict__ b_struct,
    const float* __restrict__ wmg, float* __restrict__ stats)
{
    __shared__ float T[256][65];    // 66,560 B
    __shared__ float Wc[64][12];    //  3,072 B
    int t = threadIdx.x;
    int base = blockIdx.x * 256;

    if (t < 64) {
        int d = t;
        Wc[d][0] = W_edge[d];
        Wc[d][1] = W_struct[d];
        #pragma unroll
        for (int i = 0; i < 8; ++i) Wc[d][2 + i] = W_time[i * 64 + d];
        Wc[d][10] = b_edge[d] + b_time[d] + 2.f * b_struct[d];
        Wc[d][11] = 0.f;
    }

    int w = t >> 6, lane = t & 63;
    #pragma unroll 4
    for (int it = 0; it < 64; ++it) {
        int row = it * 4 + w;
        int node = base + row;
        int rc = node < NUM_NODES ? node : (NUM_NODES - 1);
        T[row][lane] = proj[(size_t)rc * 64 + lane];
    }
    __syncthreads();

    float sp = 0.f, spp = 0.f;
    float pw[11];
    #pragma unroll
    for (int j = 0; j < 11; ++j) pw[j] = 0.f;

    for (int d = 0; d < 64; ++d) {
        float p = T[t][d];
        f32x4 c0 = *(const f32x4*)&Wc[d][0];
        f32x4 c1 = *(const f32x4*)&Wc[d][4];
        f32x4 c2 = *(const f32x4*)&Wc[d][8];
        sp += p;
        spp = fmaf(p, p, spp);
        pw[0] = fmaf(p, c0.x, pw[0]);
        pw[1] = fmaf(p, c0.y, pw[1]);
        pw[2] = fmaf(p, c0.z, pw[2]);
        pw[3] = fmaf(p, c0.w, pw[3]);
        pw[4] = fmaf(p, c1.x, pw[4]);
        pw[5] = fmaf(p, c1.y, pw[5]);
        pw[6] = fmaf(p, c1.z, pw[6]);
        pw[7] = fmaf(p, c1.w, pw[7]);
        pw[8] = fmaf(p, c2.x, pw[8]);
        pw[9] = fmaf(p, c2.y, pw[9]);
        pw[10] = fmaf(p, c2.z, pw[10]);
    }

    int node = base + t;
    if (node < NUM_NODES) {
        float o[16];
        o[0] = sp * (1.f / 64.f);
        o[1] = spp - sp * sp * (1.f / 64.f);
        #pragma unroll
        for (int j = 0; j < 11; ++j) o[2 + j] = pw[j] - sp * wmg[j];
        o[13] = 0.f; o[14] = 0.f; o[15] = 0.f;
        float* dst = stats + (size_t)node * 16;
        #pragma unroll
        for (int q = 0; q < 4; ++q) *(f32x4*)(dst + q * 4) = *(f32x4*)&o[q * 4];
    }
}

// ---------------------------------------------------------------------------
// k_main: one block per sample b. 256 threads = 4 waves.
//   Staging: per-neighbor scalars + closed-form LN stats (mu, rstd) -> LDS.
//   Phase A: pure-FMA fused features, normalize with (rstd, -mu*rstd), bf16 pack.
//   Phase B: MFMA; Phase C: chain GCN + pool; Phase D: output proj.
// ---------------------------------------------------------------------------
__global__ __launch_bounds__(256) void k_main(
    const int* __restrict__ ids, const int* __restrict__ eids,
    const float* __restrict__ times, const int* __restrict__ dst_ids,
    const float* __restrict__ edge_raw,
    const float* __restrict__ W_edge, const float* __restrict__ b_edge,
    const float* __restrict__ W_time, const float* __restrict__ b_time,
    const float* __restrict__ W_struct, const float* __restrict__ b_struct,
    const float* __restrict__ w_tenc, const float* __restrict__ b_tenc,
    const float* __restrict__ b_gcn, const float* __restrict__ W_out,
    const float* __restrict__ b_out,
    const float* __restrict__ proj, const int* __restrict__ skill,
    const unsigned short* __restrict__ WgT, const float* __restrict__ hb,
    const float* __restrict__ wmg, const float* __restrict__ Mg,
    const float* __restrict__ stats,
    float* __restrict__ out)
{
    __shared__ int ids_s[N_];
    __shared__ f32x2 ec_s[N_];                // (edge_col, struct_count)
    __shared__ f32x2 mr_s[N_];                // (rstd, -mu*rstd)
    __shared__ float tenc_s[N_][8];
    __shared__ unsigned short xh[112 * 64];   // bf16, 16B-chunk XOR-swizzled per row
    __shared__ float pooled[64];
    __shared__ int vcnt_w[4];

    int b = blockIdx.x;
    int t = threadIdx.x;
    int lane = t & 63, w = t >> 6;

    int dstb = dst_ids[b];
    int skdst = skill[dstb];

    // per-lane params (uniform-address -> scalar loads)
    float wedge = W_edge[lane], wstr = W_struct[lane];
    float biasr = b_edge[lane] + b_time[lane] + 2.f * b_struct[lane];
    float wtime[8];
    #pragma unroll
    for (int i = 0; i < 8; ++i) wtime[i] = W_time[i * 64 + lane];

    // -------- Stage: per-neighbor scalars + LN stats --------
    int idx_c = t < N_ ? t : N_ - 1;
    int id_t = ids[b * N_ + idx_c];
    float tm_t = times[b * N_ + idx_c];
    int ei_t = eids[b * N_ + idx_c];
    float e_t = edge_raw[(size_t)ei_t * 128];
    int sk_t = skill[id_t];
    unsigned long long bal = __ballot((t < N_) && (id_t > 0));
    if (lane == 0) vcnt_w[w] = __popcll(bal);
    if (t < N_) {
        ids_s[t] = id_t;
        float c = (id_t == dstb ? 1.f : 0.f) + (sk_t == skdst ? 1.f : 0.f);
        f32x2 ec = {e_t, c};
        ec_s[t] = ec;

        float u[11];
        u[0] = e_t;
        u[1] = c;
        #pragma unroll
        for (int i = 0; i < 8; ++i) {
            float tc = __cosf(fmaf(tm_t, w_tenc[i], b_tenc[i]));
            tenc_s[t][i] = tc;
            u[2 + i] = tc;
        }
        u[10] = 1.f;

        const f32x4* sp = (const f32x4*)(stats + (size_t)id_t * 16);
        f32x4 s0 = sp[0], s1 = sp[1], s2 = sp[2], s3 = sp[3];
        float pwv[11] = {s0.z, s0.w, s1.x, s1.y, s1.z, s1.w,
                         s2.x, s2.y, s2.z, s2.w, s3.x};
        float mu = s0.x;
        float q = s0.y;
        #pragma unroll
        for (int j = 0; j < 11; ++j) {
            mu = fmaf(u[j], wmg[j], mu);
            q = fmaf(2.f * u[j], pwv[j], q);
        }
        #pragma unroll
        for (int j = 0; j < 11; ++j) {
            float tj = 0.f;
            #pragma unroll
            for (int k = 0; k < 11; ++k) tj = fmaf(Mg[j * 11 + k], u[k], tj);
            q = fmaf(u[j], tj, q);
        }
        float var = fmaxf(q, 0.f) * (1.f / 64.f);
        float rstd = rsqrtf(var + 1e-5f);
        f32x2 mr = {rstd, -mu * rstd};
        mr_s[t] = mr;
    }
    if (t < 96) {                              // zero pad xh rows 100..111 (1536B)
        f32x4 z = {0.f, 0.f, 0.f, 0.f};
        *(f32x4*)((char*)xh + 100 * 128 + t * 16) = z;
    }
    __syncthreads();
    int v = vcnt_w[0] + vcnt_w[1] + vcnt_w[2] + vcnt_w[3];

    // -------- Phase A: 5-deep pipelined proj gather, no reductions --------
    float pc[5], pn[5];
    #pragma unroll
    for (int j = 0; j < 5; ++j)
        pc[j] = proj[(size_t)ids_s[j * 4 + w] * 64 + lane];

    #pragma unroll
    for (int g = 0; g < 5; ++g) {
        if (g < 4) {
            #pragma unroll
            for (int j = 0; j < 5; ++j)
                pn[j] = proj[(size_t)ids_s[(5 * (g + 1) + j) * 4 + w] * 64 + lane];
        }
        #pragma unroll
        for (int j = 0; j < 5; ++j) {
            int n = (5 * g + j) * 4 + w;
            f32x2 ec = ec_s[n];
            f32x2 mr = mr_s[n];
            f32x4 t0 = *(const f32x4*)&tenc_s[n][0];
            f32x4 t1 = *(const f32x4*)&tenc_s[n][4];
            float tf = t0.x * wtime[0];
            tf = fmaf(t0.y, wtime[1], tf);
            tf = fmaf(t0.z, wtime[2], tf);
            tf = fmaf(t0.w, wtime[3], tf);
            tf = fmaf(t1.x, wtime[4], tf);
            tf = fmaf(t1.y, wtime[5], tf);
            tf = fmaf(t1.z, wtime[6], tf);
            tf = fmaf(t1.w, wtime[7], tf);
            float fused = pc[j] + fmaf(ec.x, wedge, tf) + fmaf(ec.y, wstr, biasr);
            float xhv = fmaf(fused, mr.x, mr.y);
            int chunk = (lane >> 3) ^ (n & 7);
            *(unsigned short*)((char*)xh + n * 128 + chunk * 16 + (lane & 7) * 2) = f2bf(xhv);
        }
        #pragma unroll
        for (int j = 0; j < 5; ++j) pc[j] = pn[j];
    }
    __syncthreads();

    // -------- Phase B: MFMA --------
    int col = 16 * w + (lane & 15);
    int kg = lane >> 4;
    s16x8 bfr0 = *(const s16x8*)(WgT + col * 64 + 0 * 32 + kg * 8);
    s16x8 bfr1 = *(const s16x8*)(WgT + col * 64 + 1 * 32 + kg * 8);

    f32x4 acc[7];
    #pragma unroll
    for (int mt = 0; mt < 7; ++mt) { f32x4 z = {0.f,0.f,0.f,0.f}; acc[mt] = z; }
    #pragma unroll
    for (int mt = 0; mt < 7; ++mt) {
        int row = mt * 16 + (lane & 15);
        int ch0 = (0 * 4 + kg) ^ (row & 7);
        int ch1 = (1 * 4 + kg) ^ (row & 7);
        s16x8 a0 = *(const s16x8*)((char*)xh + row * 128 + ch0 * 16);
        acc[mt] = __builtin_amdgcn_mfma_f32_16x16x32_bf16(a0, bfr0, acc[mt], 0, 0, 0);
        s16x8 a1 = *(const s16x8*)((char*)xh + row * 128 + ch1 * 16);
        acc[mt] = __builtin_amdgcn_mfma_f32_16x16x32_bf16(a1, bfr1, acc[mt], 0, 0, 0);
    }

    // -------- Phase C: chain + relu + pool --------
    float hbv = hb[col], bgc = b_gcn[col];
    float carry = 0.f, po = 0.f;
    #pragma unroll
    for (int mt = 0; mt < 7; ++mt) {
        float hh[4];
        hh[0] = acc[mt].x + hbv; hh[1] = acc[mt].y + hbv;
        hh[2] = acc[mt].z + hbv; hh[3] = acc[mt].w + hbv;
        float hup = __shfl_up(hh[3], 16, 64);
        float hpj = (kg > 0) ? hup : carry;
        int nb = mt * 16 + kg * 4;
        #pragma unroll
        for (int j = 0; j < 4; ++j) {
            int nn = nb + j;
            bool hin = (nn >= 1) && (nn < v);
            float a_ = hin ? 0.5f : 1.f;
            float dprev = (nn >= 2 && nn <= v) ? 0.70710678118f : 1.f;
            float coef = hin ? dprev * 0.70710678118f : 0.f;
            float o = hh[j] * a_ + coef * hpj + bgc;
            po += (nn < N_) ? fmaxf(o, 0.f) : 0.f;
            hpj = hh[j];
        }
        carry = __shfl(hh[3], 48 + (lane & 15), 64);
    }
    po += __shfl_xor(po, 16, 64);
    po += __shfl_xor(po, 32, 64);
    if (lane < 16) pooled[col] = po * (1.f / (float)N_);
    __syncthreads();

    // -------- Phase D: output projections --------
    if (w == 0) {
        float o = b_out[lane];
        #pragma unroll 8
        for (int dk = 0; dk < 64; ++dk) o = fmaf(pooled[dk], W_out[dk * 64 + lane], o);
        out[(size_t)b * 64 + lane] = o;
    } else if (w == 1) {
        float o = b_out[lane];
        const float* pd = proj + (size_t)dstb * 64;   // uniform -> scalar loads
        #pragma unroll 8
        for (int dk = 0; dk < 64; ++dk) o = fmaf(pd[dk], W_out[dk * 64 + lane], o);
        out[(size_t)(B_ + b) * 64 + lane] = o;
    }
}

// ---------------------------------------------------------------------------
extern "C" void kernel_launch(void* const* d_in, const int* in_sizes, int n_in,
                              void* d_out, int out_size, void* d_ws, size_t ws_size,
                              hipStream_t stream)
{
    const int*   ids      = (const int*)d_in[0];
    const int*   eids     = (const int*)d_in[1];
    const float* times    = (const float*)d_in[2];
    const int*   dst_ids  = (const int*)d_in[3];
    const float* node_raw = (const float*)d_in[4];
    const float* edge_raw = (const float*)d_in[5];
    const float* W_feat   = (const float*)d_in[6];
    const float* b_feat   = (const float*)d_in[7];
    const float* W_edge   = (const float*)d_in[8];
    const float* b_edge   = (const float*)d_in[9];
    const float* W_time   = (const float*)d_in[10];
    const float* b_time   = (const float*)d_in[11];
    const float* W_struct = (const float*)d_in[12];
    const float* b_struct = (const float*)d_in[13];
    const float* w_tenc   = (const float*)d_in[14];
    const float* b_tenc   = (const float*)d_in[15];
    const float* ln_g     = (const float*)d_in[16];
    const float* ln_b     = (const float*)d_in[17];
    const float* W_gcn    = (const float*)d_in[18];
    const float* b_gcn    = (const float*)d_in[19];
    const float* W_out    = (const float*)d_in[20];
    const float* b_out    = (const float*)d_in[21];

    char* ws = (char*)d_ws;
    float*          proj   = (float*)ws;                          // 12,800,000 B
    int*            skill  = (int*)(ws + 12800000);               //    200,000 B
    unsigned short* WgT    = (unsigned short*)(ws + 13000000);    //      8,192 B
    float*          hb     = (float*)(ws + 13008192);             //        256 B
    float*          wmg    = (float*)(ws + 13008448);             //         64 B
    float*          Mg     = (float*)(ws + 13008512);             //        512 B
    float*          stats  = (float*)(ws + 13100032);             //  3,200,000 B

    k_pre<<<1564, 256, 0, stream>>>(node_raw, W_feat, b_feat, W_gcn, ln_g, ln_b,
                                    W_edge, b_edge, W_time, b_time, W_struct, b_struct,
                                    proj, skill, WgT, hb, wmg, Mg);
    k_stat<<<196, 256, 0, stream>>>(proj, W_edge, b_edge, W_time, b_time,
                                    W_struct, b_struct, wmg, stats);
    k_main<<<B_, 256, 0, stream>>>(ids, eids, times, dst_ids, edge_raw,
                                   W_edge, b_edge, W_time, b_time, W_struct, b_struct,
                                   w_tenc, b_tenc, b_gcn, W_out, b_out,
                                   proj, skill, WgT, hb, wmg, Mg, stats, (float*)d_out);
}